// Round 4
// baseline (77.896 us; speedup 1.0000x reference)
//
#include <hip/hip_runtime.h>

#define NATOMS   8192
#define NVEC     (NATOMS / 4)      // 2048 float4 per row
#define BT       256
#define NB_PAIR  (NATOMS / 2)      // 4096 row-pair blocks
#define NBONDS   8192
#define NANGLES  16384
#define NDIH     24576
#define NB_BOND  ((NBONDS + NANGLES + NDIH) / BT)   // 192
#define NB_MAIN  (NB_PAIR + NB_BOND)                // 4288

// native clang vector type — accepted by __builtin_nontemporal_load
typedef float floatx4 __attribute__((ext_vector_type(4)));

// ws layout (floats): px[8192] py[8192] pz[8192] sq[8192] partial[NB_MAIN]
#define WS_PX 0
#define WS_PY NATOMS
#define WS_PZ (2 * NATOMS)
#define WS_SQ (3 * NATOMS)
#define WS_PARTIAL (4 * NATOMS)

// Replicate numpy f32: sq = (x*x + y*y) + z*z, no contraction.
__device__ __forceinline__ float sq_np(float x, float y, float z)
{
    return __fadd_rn(__fadd_rn(__fmul_rn(x, x), __fmul_rn(y, y)),
                     __fmul_rn(z, z));
}

// SoA transpose of positions + precomputed row norms (exact sq_np bits).
__global__ __launch_bounds__(BT)
void soa_kernel(const float* __restrict__ pos, float* __restrict__ ws)
{
    const int i = blockIdx.x * BT + threadIdx.x;
    if (i < NATOMS) {
        const float x = pos[3 * i + 0];
        const float y = pos[3 * i + 1];
        const float z = pos[3 * i + 2];
        ws[WS_PX + i] = x;
        ws[WS_PY + i] = y;
        ws[WS_PZ + i] = z;
        ws[WS_SQ + i] = sq_np(x, y, z);
    }
}

// ---------------------------------------------------------------------------
// Row i LJ partial for one thread (upper triangle, f32 numerics matching the
// reference's Gram-form exactly — verified bit-exact in round 2).
// sigma/eps below/on the diagonal are 0 -> contribute exactly 0.
// NT loads on the 256MB sigma/eps streams keep the hot SoA arrays resident
// in L1/L2.
// ---------------------------------------------------------------------------
__device__ __forceinline__ float lj_row(const float* __restrict__ sigma,
                                        const float* __restrict__ eps,
                                        const float* __restrict__ ws,
                                        int i, int tid)
{
    const float xi  = ws[WS_PX + i];
    const float yi  = ws[WS_PY + i];
    const float zi  = ws[WS_PZ + i];
    const float sqi = ws[WS_SQ + i];

    const float* __restrict__ srow = sigma + (size_t)i * NATOMS;
    const float* __restrict__ erow = eps   + (size_t)i * NATOMS;
    const float* __restrict__ pxp  = ws + WS_PX;
    const float* __restrict__ pyp  = ws + WS_PY;
    const float* __restrict__ pzp  = ws + WS_PZ;
    const float* __restrict__ sqp  = ws + WS_SQ;

    float acc = 0.0f;
    const int v0 = (i + 1) >> 2;   // first float4 index touching j > i

    #pragma unroll 2
    for (int v = v0 + tid; v < NVEC; v += BT) {
        const floatx4 s4 = __builtin_nontemporal_load(
            reinterpret_cast<const floatx4*>(srow + 4 * v));
        const floatx4 e4 = __builtin_nontemporal_load(
            reinterpret_cast<const floatx4*>(erow + 4 * v));
        const floatx4 px4 = *reinterpret_cast<const floatx4*>(pxp + 4 * v);
        const floatx4 py4 = *reinterpret_cast<const floatx4*>(pyp + 4 * v);
        const floatx4 pz4 = *reinterpret_cast<const floatx4*>(pzp + 4 * v);
        const floatx4 sq4 = *reinterpret_cast<const floatx4*>(sqp + 4 * v);

        #pragma unroll
        for (int k = 0; k < 4; ++k) {
            float t = __fmul_rn(xi, px4[k]);
            t = fmaf(yi, py4[k], t);
            t = fmaf(zi, pz4[k], t);
            const float d2 = __fsub_rn(__fadd_rn(sqi, sq4[k]),
                                       __fmul_rn(2.0f, t));
            const float dist  = __fadd_rn(__fsqrt_rn(fmaxf(d2, 0.0f)), 1e-9f);
            const float ratio = __fdiv_rn(s4[k], dist);
            const float r2  = __fmul_rn(ratio, ratio);
            const float r6  = __fmul_rn(__fmul_rn(r2, r2), r2);
            const float r12 = __fmul_rn(r6, r6);
            acc += 4.0f * e4[k] * (r12 - r6);
        }
    }
    return acc;
}

// ---------------------------------------------------------------------------
// Fused main kernel: blocks [0, 4096) do LJ row pairs (b, 8191-b) — constant
// 8191 pair-elements per block; blocks [4096, 4288) do bonds/angles/dihedrals.
// ---------------------------------------------------------------------------
__global__ __launch_bounds__(BT)
void main_kernel(const float* __restrict__ sigma,
                 const float* __restrict__ eps,
                 const float* __restrict__ pos,
                 const float* __restrict__ k_bond,
                 const float* __restrict__ r0,
                 const int*   __restrict__ bidx,
                 const float* __restrict__ k_angle,
                 const float* __restrict__ th0,
                 const int*   __restrict__ aidx,
                 const float* __restrict__ k_dih,
                 const float* __restrict__ phase,
                 const float* __restrict__ nmult,
                 const int*   __restrict__ didx,
                 float* __restrict__ ws)
{
    const int bid = blockIdx.x;
    const int tid = threadIdx.x;
    float e = 0.0f;

    if (bid < NB_PAIR) {
        e  = lj_row(sigma, eps, ws, bid, tid);
        e += lj_row(sigma, eps, ws, NATOMS - 1 - bid, tid);
    } else {
        const int t = (bid - NB_PAIR) * BT + tid;
        if (t < NBONDS) {
            const int a = bidx[2 * t + 0];
            const int b = bidx[2 * t + 1];
            const float xa = pos[3 * a + 0], ya = pos[3 * a + 1], za = pos[3 * a + 2];
            const float xb = pos[3 * b + 0], yb = pos[3 * b + 1], zb = pos[3 * b + 2];
            float dt2 = __fmul_rn(xa, xb);
            dt2 = fmaf(ya, yb, dt2);
            dt2 = fmaf(za, zb, dt2);
            const float d2 = __fsub_rn(__fadd_rn(sq_np(xa, ya, za), sq_np(xb, yb, zb)),
                                       __fmul_rn(2.0f, dt2));
            const float d  = __fadd_rn(__fsqrt_rn(fmaxf(d2, 0.0f)), 1e-9f);
            const float dd = d - r0[t];
            e = 0.5f * k_bond[t] * dd * dd;
        } else if (t < NBONDS + NANGLES) {
            const int u = t - NBONDS;
            const int a = aidx[3 * u + 0];
            const int b = aidx[3 * u + 1];
            const int c = aidx[3 * u + 2];
            const float v1x = pos[3 * b + 0] - pos[3 * a + 0];
            const float v1y = pos[3 * b + 1] - pos[3 * a + 1];
            const float v1z = pos[3 * b + 2] - pos[3 * a + 2];
            const float v2x = pos[3 * b + 0] - pos[3 * c + 0];
            const float v2y = pos[3 * b + 1] - pos[3 * c + 1];
            const float v2z = pos[3 * b + 2] - pos[3 * c + 2];
            const float dot = fmaf(v1x, v2x, fmaf(v1y, v2y, v1z * v2z));
            const float n1  = sqrtf(fmaf(v1x, v1x, fmaf(v1y, v1y, v1z * v1z)));
            const float n2  = sqrtf(fmaf(v2x, v2x, fmaf(v2y, v2y, v2z * v2z)));
            float ca = dot / (n1 * n2);
            ca = fminf(1.0f, fmaxf(-1.0f, ca));
            const float ang = acosf(ca);
            const float dth = ang - th0[u];
            e = 0.5f * k_angle[u] * dth * dth;
        } else {
            const int u = t - NBONDS - NANGLES;
            const int a = didx[4 * u + 0];
            const int b = didx[4 * u + 1];
            const int c = didx[4 * u + 2];
            const int d = didx[4 * u + 3];
            const float w1x = pos[3 * b + 0] - pos[3 * a + 0];
            const float w1y = pos[3 * b + 1] - pos[3 * a + 1];
            const float w1z = pos[3 * b + 2] - pos[3 * a + 2];
            const float w2x = pos[3 * c + 0] - pos[3 * b + 0];
            const float w2y = pos[3 * c + 1] - pos[3 * b + 1];
            const float w2z = pos[3 * c + 2] - pos[3 * b + 2];
            const float w3x = pos[3 * d + 0] - pos[3 * c + 0];
            const float w3y = pos[3 * d + 1] - pos[3 * c + 1];
            const float w3z = pos[3 * d + 2] - pos[3 * c + 2];
            const float n1x = w1y * w2z - w1z * w2y;
            const float n1y = w1z * w2x - w1x * w2z;
            const float n1z = w1x * w2y - w1y * w2x;
            const float n2x = w2y * w3z - w2z * w3y;
            const float n2y = w2z * w3x - w2x * w3z;
            const float n2z = w2x * w3y - w2y * w3x;
            const float dot12 = fmaf(n1x, n2x, fmaf(n1y, n2y, n1z * n2z));
            const float nw1 = sqrtf(fmaf(w1x, w1x, fmaf(w1y, w1y, w1z * w1z)));
            const float nw2 = sqrtf(fmaf(w2x, w2x, fmaf(w2y, w2y, w2z * w2z)));
            const float nn1 = sqrtf(fmaf(n1x, n1x, fmaf(n1y, n1y, n1z * n1z)));
            const float nn2 = sqrtf(fmaf(n2x, n2x, fmaf(n2y, n2y, n2z * n2z)));
            const float cos_d = dot12 / (nw1 * nw2);
            const float cx = n1y * n2z - n1z * n2y;
            const float cy = n1z * n2x - n1x * n2z;
            const float cz = n1x * n2y - n1y * n2x;
            const float sden = nw2 * nn1 * nn2;
            const float sin_d = fmaf(cx, w2x, fmaf(cy, w2y, cz * w2z)) / sden;
            const float dih = atan2f(sin_d, cos_d);
            e = 0.5f * k_dih[u] * (1.0f + cosf(nmult[u] * dih - phase[u]));
        }
    }

    #pragma unroll
    for (int off = 32; off > 0; off >>= 1)
        e += __shfl_down(e, off, 64);
    __shared__ float red[BT / 64];
    if ((tid & 63) == 0) red[tid >> 6] = e;
    __syncthreads();
    if (tid == 0)
        ws[WS_PARTIAL + bid] = red[0] + red[1] + red[2] + red[3];
}

// ---------------------------------------------------------------------------
// Final deterministic reduction (double accumulation), writes scalar f32.
// ---------------------------------------------------------------------------
#define RT 1024
__global__ __launch_bounds__(RT)
void reduce_kernel(const float* __restrict__ partial, int n,
                   float* __restrict__ out)
{
    double s = 0.0;
    for (int i = threadIdx.x; i < n; i += RT)
        s += (double)partial[i];
    #pragma unroll
    for (int off = 32; off > 0; off >>= 1)
        s += __shfl_down(s, off, 64);
    __shared__ double red[RT / 64];
    if ((threadIdx.x & 63) == 0) red[threadIdx.x >> 6] = s;
    __syncthreads();
    if (threadIdx.x == 0) {
        double t = 0.0;
        #pragma unroll
        for (int w = 0; w < RT / 64; ++w) t += red[w];
        out[0] = (float)t;
    }
}

extern "C" void kernel_launch(void* const* d_in, const int* in_sizes, int n_in,
                              void* d_out, int out_size, void* d_ws, size_t ws_size,
                              hipStream_t stream)
{
    const float* pos   = (const float*)d_in[0];
    const float* sigma = (const float*)d_in[1];
    const float* eps   = (const float*)d_in[2];
    const float* kb    = (const float*)d_in[3];
    const float* r0    = (const float*)d_in[4];
    const int*   bidx  = (const int*)  d_in[5];
    const float* ka    = (const float*)d_in[6];
    const float* th0   = (const float*)d_in[7];
    const int*   aidx  = (const int*)  d_in[8];
    const float* kd    = (const float*)d_in[9];
    const float* ph    = (const float*)d_in[10];
    const float* nm    = (const float*)d_in[11];
    const int*   didx  = (const int*)  d_in[12];

    float* ws  = (float*)d_ws;
    float* out = (float*)d_out;

    soa_kernel<<<NATOMS / BT, BT, 0, stream>>>(pos, ws);
    main_kernel<<<NB_MAIN, BT, 0, stream>>>(sigma, eps, pos, kb, r0, bidx,
                                            ka, th0, aidx, kd, ph, nm, didx, ws);
    reduce_kernel<<<1, RT, 0, stream>>>(ws + WS_PARTIAL, NB_MAIN, out);
}

// Round 5
// 55.273 us; speedup vs baseline: 1.4093x; 1.4093x over previous
//
#include <hip/hip_runtime.h>

#define NATOMS   8192
#define NVEC     (NATOMS / 4)      // 2048 float4 per row
#define BT       256
#define NB_LJ    NATOMS            // one block per row
#define NBONDS   8192
#define NANGLES  16384
#define NDIH     24576
#define NB_BOND  ((NBONDS + NANGLES + NDIH) / BT)   // 192

// Replicate numpy f32: sq = (x*x + y*y) + z*z, no contraction.
__device__ __forceinline__ float sq_np(float x, float y, float z)
{
    return __fadd_rn(__fadd_rn(__fmul_rn(x, x), __fmul_rn(y, y)),
                     __fmul_rn(z, z));
}

// One float4 chunk of the reference-exact LJ row computation.
// (Gram-form d2, fma-chain dot, rn-chain r6/r12 — bit-exact in round 2.)
__device__ __forceinline__ float lj_chunk(const float* __restrict__ srow,
                                          const float* __restrict__ erow,
                                          const float* __restrict__ pos,
                                          float xi, float yi, float zi,
                                          float sqi, int v)
{
    const float4 s4 = *reinterpret_cast<const float4*>(srow + 4 * v);
    const float4 e4 = *reinterpret_cast<const float4*>(erow + 4 * v);
    const float4 p0 = *reinterpret_cast<const float4*>(pos + 12 * v + 0);
    const float4 p1 = *reinterpret_cast<const float4*>(pos + 12 * v + 4);
    const float4 p2 = *reinterpret_cast<const float4*>(pos + 12 * v + 8);

    const float px[4] = { p0.x, p0.w, p1.z, p2.y };
    const float py[4] = { p0.y, p1.x, p1.w, p2.z };
    const float pz[4] = { p0.z, p1.y, p2.x, p2.w };
    const float ss[4] = { s4.x, s4.y, s4.z, s4.w };
    const float ee[4] = { e4.x, e4.y, e4.z, e4.w };

    float acc = 0.0f;
    #pragma unroll
    for (int k = 0; k < 4; ++k) {
        float t = __fmul_rn(xi, px[k]);
        t = fmaf(yi, py[k], t);
        t = fmaf(zi, pz[k], t);
        const float sqj = sq_np(px[k], py[k], pz[k]);
        const float d2  = __fsub_rn(__fadd_rn(sqi, sqj),
                                    __fmul_rn(2.0f, t));
        const float dist  = __fadd_rn(__fsqrt_rn(fmaxf(d2, 0.0f)), 1e-9f);
        const float ratio = __fdiv_rn(ss[k], dist);
        const float r2  = __fmul_rn(ratio, ratio);
        const float r6  = __fmul_rn(__fmul_rn(r2, r2), r2);
        const float r12 = __fmul_rn(r6, r6);
        acc += 4.0f * ee[k] * (r12 - r6);
    }
    return acc;
}

// ---------------------------------------------------------------------------
// LJ pair energy over the upper triangle; one block per row; manual 2x unroll
// of the streaming loop for more outstanding stream loads per wave.
// sigma/eps at j <= i are 0 -> contribute exactly 0.
// ---------------------------------------------------------------------------
__global__ __launch_bounds__(BT)
void lj_kernel(const float* __restrict__ pos,
               const float* __restrict__ sigma,
               const float* __restrict__ eps,
               float* __restrict__ partial)
{
    const int i   = blockIdx.x;
    const int tid = threadIdx.x;

    const float xi = pos[3 * i + 0];
    const float yi = pos[3 * i + 1];
    const float zi = pos[3 * i + 2];
    const float sqi = sq_np(xi, yi, zi);

    const float* __restrict__ srow = sigma + (size_t)i * NATOMS;
    const float* __restrict__ erow = eps   + (size_t)i * NATOMS;

    float acc = 0.0f;
    const int v0 = (i + 1) >> 2;   // first float4 index touching j > i

    for (int v = v0 + tid; v < NVEC; v += 2 * BT) {
        acc += lj_chunk(srow, erow, pos, xi, yi, zi, sqi, v);
        const int v2 = v + BT;
        if (v2 < NVEC)
            acc += lj_chunk(srow, erow, pos, xi, yi, zi, sqi, v2);
    }

    // block reduction: wave shuffle then cross-wave via LDS
    #pragma unroll
    for (int off = 32; off > 0; off >>= 1)
        acc += __shfl_down(acc, off, 64);
    __shared__ float red[BT / 64];
    if ((tid & 63) == 0) red[tid >> 6] = acc;
    __syncthreads();
    if (tid == 0)
        partial[i] = red[0] + red[1] + red[2] + red[3];
}

// ---------------------------------------------------------------------------
// Bonds, angles, dihedrals — one work item per thread (separate kernel so its
// transcendental-heavy VGPR usage doesn't cut the LJ kernel's occupancy —
// fusing them cost 20 us in round 4).
// ---------------------------------------------------------------------------
__global__ __launch_bounds__(BT)
void bonded_kernel(const float* __restrict__ pos,
                   const float* __restrict__ k_bond,
                   const float* __restrict__ r0,
                   const int*   __restrict__ bidx,
                   const float* __restrict__ k_angle,
                   const float* __restrict__ th0,
                   const int*   __restrict__ aidx,
                   const float* __restrict__ k_dih,
                   const float* __restrict__ phase,
                   const float* __restrict__ nmult,
                   const int*   __restrict__ didx,
                   float* __restrict__ partial)
{
    const int t = blockIdx.x * BT + threadIdx.x;
    float e = 0.0f;

    if (t < NBONDS) {
        const int a = bidx[2 * t + 0];
        const int b = bidx[2 * t + 1];
        const float xa = pos[3 * a + 0], ya = pos[3 * a + 1], za = pos[3 * a + 2];
        const float xb = pos[3 * b + 0], yb = pos[3 * b + 1], zb = pos[3 * b + 2];
        float dt2 = __fmul_rn(xa, xb);
        dt2 = fmaf(ya, yb, dt2);
        dt2 = fmaf(za, zb, dt2);
        const float d2 = __fsub_rn(__fadd_rn(sq_np(xa, ya, za), sq_np(xb, yb, zb)),
                                   __fmul_rn(2.0f, dt2));
        const float d  = __fadd_rn(__fsqrt_rn(fmaxf(d2, 0.0f)), 1e-9f);
        const float dd = d - r0[t];
        e = 0.5f * k_bond[t] * dd * dd;
    } else if (t < NBONDS + NANGLES) {
        const int u = t - NBONDS;
        const int a = aidx[3 * u + 0];
        const int b = aidx[3 * u + 1];
        const int c = aidx[3 * u + 2];
        const float v1x = pos[3 * b + 0] - pos[3 * a + 0];
        const float v1y = pos[3 * b + 1] - pos[3 * a + 1];
        const float v1z = pos[3 * b + 2] - pos[3 * a + 2];
        const float v2x = pos[3 * b + 0] - pos[3 * c + 0];
        const float v2y = pos[3 * b + 1] - pos[3 * c + 1];
        const float v2z = pos[3 * b + 2] - pos[3 * c + 2];
        const float dot = fmaf(v1x, v2x, fmaf(v1y, v2y, v1z * v2z));
        const float n1  = sqrtf(fmaf(v1x, v1x, fmaf(v1y, v1y, v1z * v1z)));
        const float n2  = sqrtf(fmaf(v2x, v2x, fmaf(v2y, v2y, v2z * v2z)));
        float ca = dot / (n1 * n2);
        ca = fminf(1.0f, fmaxf(-1.0f, ca));
        const float ang = acosf(ca);
        const float dth = ang - th0[u];
        e = 0.5f * k_angle[u] * dth * dth;
    } else {
        const int u = t - NBONDS - NANGLES;
        const int a = didx[4 * u + 0];
        const int b = didx[4 * u + 1];
        const int c = didx[4 * u + 2];
        const int d = didx[4 * u + 3];
        const float w1x = pos[3 * b + 0] - pos[3 * a + 0];
        const float w1y = pos[3 * b + 1] - pos[3 * a + 1];
        const float w1z = pos[3 * b + 2] - pos[3 * a + 2];
        const float w2x = pos[3 * c + 0] - pos[3 * b + 0];
        const float w2y = pos[3 * c + 1] - pos[3 * b + 1];
        const float w2z = pos[3 * c + 2] - pos[3 * b + 2];
        const float w3x = pos[3 * d + 0] - pos[3 * c + 0];
        const float w3y = pos[3 * d + 1] - pos[3 * c + 1];
        const float w3z = pos[3 * d + 2] - pos[3 * c + 2];
        const float n1x = w1y * w2z - w1z * w2y;
        const float n1y = w1z * w2x - w1x * w2z;
        const float n1z = w1x * w2y - w1y * w2x;
        const float n2x = w2y * w3z - w2z * w3y;
        const float n2y = w2z * w3x - w2x * w3z;
        const float n2z = w2x * w3y - w2y * w3x;
        const float dot12 = fmaf(n1x, n2x, fmaf(n1y, n2y, n1z * n2z));
        const float nw1 = sqrtf(fmaf(w1x, w1x, fmaf(w1y, w1y, w1z * w1z)));
        const float nw2 = sqrtf(fmaf(w2x, w2x, fmaf(w2y, w2y, w2z * w2z)));
        const float nn1 = sqrtf(fmaf(n1x, n1x, fmaf(n1y, n1y, n1z * n1z)));
        const float nn2 = sqrtf(fmaf(n2x, n2x, fmaf(n2y, n2y, n2z * n2z)));
        const float cos_d = dot12 / (nw1 * nw2);
        const float cx = n1y * n2z - n1z * n2y;
        const float cy = n1z * n2x - n1x * n2z;
        const float cz = n1x * n2y - n1y * n2x;
        const float sden = nw2 * nn1 * nn2;
        const float sin_d = fmaf(cx, w2x, fmaf(cy, w2y, cz * w2z)) / sden;
        const float dih = atan2f(sin_d, cos_d);
        e = 0.5f * k_dih[u] * (1.0f + cosf(nmult[u] * dih - phase[u]));
    }

    #pragma unroll
    for (int off = 32; off > 0; off >>= 1)
        e += __shfl_down(e, off, 64);
    __shared__ float red[BT / 64];
    if ((threadIdx.x & 63) == 0) red[threadIdx.x >> 6] = e;
    __syncthreads();
    if (threadIdx.x == 0)
        partial[NB_LJ + blockIdx.x] = red[0] + red[1] + red[2] + red[3];
}

// ---------------------------------------------------------------------------
// Final deterministic reduction (double accumulation), writes scalar f32.
// ---------------------------------------------------------------------------
#define RT 1024
__global__ __launch_bounds__(RT)
void reduce_kernel(const float* __restrict__ partial, int n,
                   float* __restrict__ out)
{
    double s = 0.0;
    for (int i = threadIdx.x; i < n; i += RT)
        s += (double)partial[i];
    #pragma unroll
    for (int off = 32; off > 0; off >>= 1)
        s += __shfl_down(s, off, 64);
    __shared__ double red[RT / 64];
    if ((threadIdx.x & 63) == 0) red[threadIdx.x >> 6] = s;
    __syncthreads();
    if (threadIdx.x == 0) {
        double t = 0.0;
        #pragma unroll
        for (int w = 0; w < RT / 64; ++w) t += red[w];
        out[0] = (float)t;
    }
}

extern "C" void kernel_launch(void* const* d_in, const int* in_sizes, int n_in,
                              void* d_out, int out_size, void* d_ws, size_t ws_size,
                              hipStream_t stream)
{
    const float* pos   = (const float*)d_in[0];
    const float* sigma = (const float*)d_in[1];
    const float* eps   = (const float*)d_in[2];
    const float* kb    = (const float*)d_in[3];
    const float* r0    = (const float*)d_in[4];
    const int*   bidx  = (const int*)  d_in[5];
    const float* ka    = (const float*)d_in[6];
    const float* th0   = (const float*)d_in[7];
    const int*   aidx  = (const int*)  d_in[8];
    const float* kd    = (const float*)d_in[9];
    const float* ph    = (const float*)d_in[10];
    const float* nm    = (const float*)d_in[11];
    const int*   didx  = (const int*)  d_in[12];

    float* ws  = (float*)d_ws;
    float* out = (float*)d_out;

    lj_kernel<<<NB_LJ, BT, 0, stream>>>(pos, sigma, eps, ws);
    bonded_kernel<<<NB_BOND, BT, 0, stream>>>(pos, kb, r0, bidx, ka, th0, aidx,
                                              kd, ph, nm, didx, ws);
    reduce_kernel<<<1, RT, 0, stream>>>(ws, NB_LJ + NB_BOND, out);
}